// Round 15
// baseline (251.510 us; speedup 1.0000x reference)
//
#include <hip/hip_runtime.h>

#define NN 74240      // nodes
#define NE 593920     // edges
#define DIN 75
#define DD 128
#define NL 3
#define EPS 1e-5f
#define NB 290        // scan blocks: 290*256 == NN
#define NT (NN / 64)  // 1160 row-tiles for k_layer
#define NGB (NN / 4)  // 18560 gather blocks
#define NREP 64       // replicated BN-sum buffers
#define SROWX 104     // LDS X row stride (shorts): 208B -> 2-way bank alias (free)

// k_pre block-range dispatch: Wi frag prepack (48) + zero sumrep/cnt (121)
#define NB_WIFRAG 48                       // 12288 shorts / 256
#define NZ4 ((NL * NREP * 256 + NN) / 4)   // 30848 int4-words to zero
#define NB_ZERO  ((NZ4 + 255) / 256)       // 121
#define NB_PRE   (NB_WIFRAG + NB_ZERO)     // 169

// k_setup block-range dispatch
#define NB_INIT  (NN / 64)                // 1160
#define SB_WPREP NB_INIT                  // 1160
#define NB_WPREP ((NL * 2 * 16384) / 256) // 384
#define SB_HIST  (SB_WPREP + NB_WPREP)    // 1544
#define NB_HIST  (NE / 256)               // 2320
#define SB_PREP  (SB_HIST + NB_HIST)      // 3864
#define NB_SETUP (SB_PREP + 1)            // 3865

typedef __attribute__((ext_vector_type(8))) short short8;   // 8 bf16 = 4 VGPRs (MFMA A/B frag)
typedef __attribute__((ext_vector_type(4))) float f32x4;    // MFMA C/D frag

// fp32 -> bf16 with round-to-nearest-even
static __device__ __forceinline__ unsigned short f2bf(float f) {
    union { float f; unsigned u; } v; v.f = f;
    unsigned u = v.u;
    unsigned r = (u + 0x7fffu + ((u >> 16) & 1u)) >> 16;
    return (unsigned short)r;
}

// bf16 -> fp32 (exact)
static __device__ __forceinline__ float bf2f(unsigned short s) {
    union { unsigned u; float f; } v; v.u = ((unsigned)s) << 16; return v.f;
}

// ---------------- pre: Wi frag-prepack (bf16, K padded 75->96) | zero scratch ------
__global__ __launch_bounds__(256) void k_pre(const float* __restrict__ Wi,
                                             unsigned short* __restrict__ wifrag,
                                             int* __restrict__ zbase) {
    const int tid = threadIdx.x;
    const int b = blockIdx.x;
    if (b < NB_WIFRAG) {
        // frag flat idx e = ((s*8+t)*64 + lane)*8 + j ; k=s*32+(lane>>4)*8+j,
        // n=t*16+(lane&15). k>=75 -> 0.
        const int e = b * 256 + tid;
        const int j = e & 7;
        const int lane = (e >> 3) & 63;
        const int st = e >> 9;
        const int s = st >> 3, t = st & 7;
        const int k = s * 32 + (lane >> 4) * 8 + j;
        const int n = t * 16 + (lane & 15);
        wifrag[e] = (k < DIN) ? f2bf(Wi[k * DD + n]) : (unsigned short)0;
    } else {
        const int zi = (b - NB_WIFRAG) * 256 + tid;   // int4 index
        if (zi < NZ4) {
            ((int4*)zbase)[zi] = (int4){0, 0, 0, 0};
        }
    }
}

// ---------------- fused setup: init GEMM (MFMA, frag-fed) | wprep | hist | ab0 -----
__global__ __launch_bounds__(256) void k_setup(const float* __restrict__ X,
                                               const unsigned short* __restrict__ wifrag,
                                               unsigned short* __restrict__ hb,
                                               const float* __restrict__ Wg,
                                               const float* __restrict__ Wr,
                                               unsigned short* __restrict__ wf,
                                               const int* __restrict__ dst,
                                               int* __restrict__ cnt,
                                               float* __restrict__ ab0) {
    __shared__ unsigned short sXb[64 * SROWX];    // 13312 B (init branch only)
    const int tid = threadIdx.x;
    const int b = blockIdx.x;
    if (b < NB_INIT) {
        // ---- init GEMM via MFMA: h_bf16 = bf16(X @ W_init), K padded 75->96 ----
        const int r0 = b * 64;
        {   // stage 64x75 X: coalesced float4 (1200 vecs) + computed row/col
            const float4* Xv = (const float4*)(X + (size_t)r0 * DIN);  // 16B-aligned
            #pragma unroll
            for (int i = 0; i < 5; ++i) {
                const int vi = tid + i * 256;
                if (vi < 1200) {
                    const float4 v = Xv[vi];
                    const int f0 = vi * 4;
                    int r = f0 / 75;
                    int c = f0 - r * 75;
                    sXb[r * SROWX + c] = f2bf(v.x);
                    ++c; if (c == DIN) { c = 0; ++r; } sXb[r * SROWX + c] = f2bf(v.y);
                    ++c; if (c == DIN) { c = 0; ++r; } sXb[r * SROWX + c] = f2bf(v.z);
                    ++c; if (c == DIN) { c = 0; ++r; } sXb[r * SROWX + c] = f2bf(v.w);
                }
            }
            // zero pad cols 75..103 (29 per row)
            for (int p = tid; p < 64 * (SROWX - DIN); p += 256) {
                const int r = p / (SROWX - DIN);
                const int c = DIN + (p - r * (SROWX - DIN));
                sXb[r * SROWX + c] = 0;
            }
        }
        __syncthreads();
        const int w = tid >> 6;
        const int lane = tid & 63;
        const int ln15 = lane & 15;
        const int q = lane >> 4;
        const short8* __restrict__ wif = (const short8*)wifrag;   // 1536 short8
        f32x4 acc[8];
        #pragma unroll
        for (int t = 0; t < 8; ++t) acc[t] = (f32x4){0.f, 0.f, 0.f, 0.f};
        #pragma unroll
        for (int s = 0; s < 3; ++s) {
            const int ks = s * 32 + q * 8;
            const short8 af = *(const short8*)&sXb[(w * 16 + ln15) * SROWX + ks];
            #pragma unroll
            for (int t = 0; t < 8; ++t) {
                const short8 bfr = wif[(s * 8 + t) * 64 + lane];
                acc[t] = __builtin_amdgcn_mfma_f32_16x16x32_bf16(af, bfr, acc[t], 0, 0, 0);
            }
        }
        // C/D: col = t*16+ln15, row = r0 + w*16 + q*4 + r
        #pragma unroll
        for (int t = 0; t < 8; ++t) {
            #pragma unroll
            for (int r = 0; r < 4; ++r) {
                hb[(size_t)(r0 + w * 16 + q * 4 + r) * DD + t * 16 + ln15] = f2bf(acc[t][r]);
            }
        }
    } else if (b < SB_HIST) {
        // ---- weight prepack: fp32 [k][n] -> frag-ordered bf16 (consumed by k_layer) --
        const int gt = (b - SB_WPREP) * 256 + tid;
        const int l = gt >> 15;
        const int m = (gt >> 14) & 1;
        const int e = gt & 16383;
        const int k = e >> 7, n = e & 127;
        const float* W = (m == 0 ? Wg : Wr) + l * 16384;
        const float v = W[e];
        const int s = k >> 5, q = (k >> 3) & 3, j = k & 7, t = n >> 4;
        const int ln = (q << 4) | (n & 15);
        const int idx = ((s * 8 + t) * 64 + ln) * 8 + j;
        wf[(l * 2 + m) * 16384 + idx] = f2bf(v);
    } else if (b < SB_PREP) {
        // ---- degree histogram ----
        const int e = (b - SB_HIST) * 256 + tid;
        atomicAdd(&cnt[dst[e]], 1);
    } else {
        // ---- identity affine for layer-0 input ----
        ab0[tid] = (tid < 128) ? 1.0f : 0.0f;
    }
}

// ---------------- CSR build: scan1 -> scan3 (bsum-based parallel prefix) -> fill ----
// (round-10 lesson: merging these turns the bsum prefix into a 289-iter serial chain)
__global__ __launch_bounds__(256) void k_scan1(const int* __restrict__ cnt,
                                               int* __restrict__ bsum) {
    const int tid = threadIdx.x;
    int v = cnt[blockIdx.x * 256 + tid];
    #pragma unroll
    for (int off = 1; off < 64; off <<= 1) v += __shfl_xor(v, off, 64);
    __shared__ int ws[4];
    if ((tid & 63) == 0) ws[tid >> 6] = v;
    __syncthreads();
    if (tid == 0) bsum[blockIdx.x] = ws[0] + ws[1] + ws[2] + ws[3];
}

__global__ __launch_bounds__(256) void k_scan3(const int* __restrict__ cnt,
                                               const int* __restrict__ bsum,
                                               int* __restrict__ rowptr,
                                               int* __restrict__ offs) {
    const int tid = threadIdx.x;
    const int b = blockIdx.x;
    const int t = b * 256 + tid;
    const int lane = tid & 63;
    __shared__ int ws[4];
    __shared__ int ws2[4];
    __shared__ int sBoff;
    // exclusive block base (parallel over threads: <=2 elements each)
    int part = 0;
    for (int i = tid; i < b; i += 256) part += bsum[i];
    #pragma unroll
    for (int off = 1; off < 64; off <<= 1) part += __shfl_xor(part, off, 64);
    if (lane == 0) ws2[tid >> 6] = part;
    __syncthreads();
    if (tid == 0) sBoff = ws2[0] + ws2[1] + ws2[2] + ws2[3];
    // in-block inclusive scan of cnt
    const int v = cnt[t];
    int inc = v;
    #pragma unroll
    for (int off = 1; off < 64; off <<= 1) {
        const int u = __shfl_up(inc, off, 64);
        if (lane >= off) inc += u;
    }
    if (lane == 63) ws[tid >> 6] = inc;
    __syncthreads();
    const int w = tid >> 6;
    int waveoff = 0;
    for (int i = 0; i < 4; ++i) waveoff += (i < w) ? ws[i] : 0;
    const int excl = sBoff + waveoff + inc - v;
    rowptr[t] = excl;
    offs[t] = excl;
    if (b == NB - 1 && tid == 255) rowptr[NN] = NE;
}

__global__ __launch_bounds__(256) void k_fill(const int* __restrict__ src,
                                              const int* __restrict__ dst,
                                              int* offs, int* __restrict__ col) {
    const int e = blockIdx.x * 256 + threadIdx.x;   // grid == NE
    const int pos = atomicAdd(&offs[dst[e]], 1);
    col[pos] = src[e];
}

// reduce NREP replicated partial-sum buffers -> affine (a,b); standalone copy used
// only for the FINAL stage (k_bn input). Per-layer stats ride inside k_gather.
__global__ __launch_bounds__(128) void k_stats(const float* __restrict__ srep,
                                               const float* __restrict__ gamma,
                                               const float* __restrict__ beta,
                                               float* __restrict__ ab) {
    const int c = threadIdx.x;
    float s = 0.f, q = 0.f;
    for (int r = 0; r < NREP; ++r) {
        s += srep[r * 256 + c];
        q += srep[r * 256 + 128 + c];
    }
    const float invN = 1.0f / (float)NN;
    const float mu = s * invN;
    const float var = q * invN - mu * mu;
    const float a = gamma[c] * rsqrtf(var + EPS);
    ab[c] = a;
    ab[128 + c] = beta[c] - a * mu;
}

// ---------------- gather (RAW sums): aggb[row] = bf16(sum_e hb[col[e]]) -------------
// 8-wide predicated loop (round-14 extension of the 4-wide win): one iteration
// issues 8 clamped row loads per half-wave, covering deg<=16 rows in a single
// L3-latency round trip (Poisson(8) degrees: ~45% of rows needed 2 iterations at
// 4-wide). Slot u accumulates into a[u&3] -- identical fp reduction order to the
// 4-wide version (slots e,e+8 -> a0 etc.), so results are bit-identical.
__global__ __launch_bounds__(256) void k_gather(const unsigned short* __restrict__ hb,
                                                const int* __restrict__ rowptr,
                                                const int* __restrict__ col,
                                                unsigned short* __restrict__ aggb,
                                                const float* __restrict__ srep,
                                                const float* __restrict__ gamma,
                                                const float* __restrict__ beta,
                                                float* __restrict__ abn) {
    if (blockIdx.x >= NGB) {
        // ---- fused BN-stats for the upcoming layer (1 block, 128 lanes) ----
        const int c = threadIdx.x;
        if (c < 128) {
            float s = 0.f, q = 0.f;
            for (int r = 0; r < NREP; ++r) {
                s += srep[r * 256 + c];
                q += srep[r * 256 + 128 + c];
            }
            const float invN = 1.0f / (float)NN;
            const float mu = s * invN;
            const float var = q * invN - mu * mu;
            const float a = gamma[c] * rsqrtf(var + EPS);
            abn[c] = a;
            abn[128 + c] = beta[c] - a * mu;
        }
        return;
    }
    const int wave = threadIdx.x >> 6;
    const int lane = threadIdx.x & 63;
    const int row = blockIdx.x * 4 + wave;   // one row per wave (round-5 lesson)
    const int eb = rowptr[row];
    const int ee = rowptr[row + 1];
    const int half = lane >> 5;
    const int f = (lane & 31) * 4;           // 4 channels per lane
    float4 a0 = {0.f,0.f,0.f,0.f}, a1 = {0.f,0.f,0.f,0.f};
    float4 a2 = {0.f,0.f,0.f,0.f}, a3 = {0.f,0.f,0.f,0.f};
    for (int e = eb + half; e < ee; e += 16) {
        int   idx[8];
        float msk[8];
        #pragma unroll
        for (int u = 0; u < 8; ++u) {
            const int eu = e + u * 2;
            const bool ok = (u == 0) || (eu < ee);
            idx[u] = col[ok ? eu : e];        // clamp to a valid edge
            msk[u] = ok ? 1.0f : 0.0f;        // mask the accumulate
        }
        ushort4 v[8];
        #pragma unroll
        for (int u = 0; u < 8; ++u)
            v[u] = *(const ushort4*)(hb + (size_t)idx[u] * DD + f);
        #pragma unroll
        for (int u = 0; u < 8; ++u) {
            const float m = msk[u];
            float4* a = (u & 3) == 0 ? &a0 : ((u & 3) == 1 ? &a1 : ((u & 3) == 2 ? &a2 : &a3));
            a->x = fmaf(m, bf2f(v[u].x), a->x);
            a->y = fmaf(m, bf2f(v[u].y), a->y);
            a->z = fmaf(m, bf2f(v[u].z), a->z);
            a->w = fmaf(m, bf2f(v[u].w), a->w);
        }
    }
    float4 s;
    s.x = (a0.x + a1.x) + (a2.x + a3.x);
    s.y = (a0.y + a1.y) + (a2.y + a3.y);
    s.z = (a0.z + a1.z) + (a2.z + a3.z);
    s.w = (a0.w + a1.w) + (a2.w + a3.w);
    s.x += __shfl_xor(s.x, 32, 64);
    s.y += __shfl_xor(s.y, 32, 64);
    s.z += __shfl_xor(s.z, 32, 64);
    s.w += __shfl_xor(s.w, 32, 64);
    if (half == 0) {
        ushort4 o;
        o.x = f2bf(s.x);
        o.y = f2bf(s.y);
        o.z = f2bf(s.z);
        o.w = f2bf(s.w);
        *(ushort4*)(aggb + (size_t)row * DD + f) = o;
    }
}

// ---------------- fused layer GEMMs via bf16 MFMA (LDS-staged B, double-buffered) ---
// One 64-row tile per block; per-s-step cooperative B staging (round-12 win).
// Affine applied HERE to both operands: agg (raw sums, needs deg*b) and hin.
#define STAGE(bf, ss) do {                                              \
    _Pragma("unroll")                                                   \
    for (int i_ = 0; i_ < 4; ++i_) {                                    \
        const int idx_ = tid + i_ * 256;                                \
        const uint4 v_ = (idx_ < 512) ? wg_u4[(ss) * 512 + idx_]        \
                                      : wr_u4[(ss) * 512 + idx_ - 512]; \
        ((uint4*)sB[bf])[idx_] = v_;                                    \
    }                                                                   \
} while (0)

__global__ __launch_bounds__(256, 4) void k_layer(const unsigned short* __restrict__ hin,
                                                  const unsigned short* __restrict__ aggb,
                                                  const int* __restrict__ rowptr,
                                                  const unsigned short* __restrict__ wfrag,
                                                  const float* __restrict__ bg,
                                                  const float* __restrict__ br,
                                                  const float* __restrict__ ab,
                                                  unsigned short* __restrict__ h2b,
                                                  float* __restrict__ sumrep) {
    __shared__ unsigned short sB[2][8192];   // [buf][bg(4096) | br(4096)] = 16KB/buf
    __shared__ float sSum[256];
    const int tid = threadIdx.x;
    sSum[tid] = 0.0f;

    const int w = tid >> 6;          // wave 0..3
    const int lane = tid & 63;
    const int ln15 = lane & 15;
    const int q = lane >> 4;
    const int r0 = blockIdx.x * 64 + w * 16;   // wave's 16-row M-tile base
    const int arow = r0 + ln15;                // row this lane's A/H frag holds
    const float deg = (float)(rowptr[arow + 1] - rowptr[arow]);   // L2-hot

    const uint4* __restrict__ wg_u4 = (const uint4*)wfrag;   // 2048 uint4 (Wg frags)
    const uint4* __restrict__ wr_u4 = wg_u4 + 2048;          // Wr frags

    f32x4 accg[8], accr[8];
    #pragma unroll
    for (int t = 0; t < 8; ++t) {
        accg[t] = (f32x4){0.f, 0.f, 0.f, 0.f};
        accr[t] = (f32x4){0.f, 0.f, 0.f, 0.f};
    }

    STAGE(0, 0);
    __syncthreads();
    int cur = 0;

    #pragma unroll
    for (int s = 0; s < 4; ++s) {
        if (s < 3) STAGE(cur ^ 1, s + 1);   // async-issue next step's frags
        const int kk = s * 32 + q * 8;
        const short8 ar = *(const short8*)(aggb + (size_t)arow * DD + kk);  // raw sums
        const short8 hr = *(const short8*)(hin + (size_t)arow * DD + kk);
        const float4 av0 = *(const float4*)(ab + kk);
        const float4 av1 = *(const float4*)(ab + kk + 4);
        const float4 bv0 = *(const float4*)(ab + 128 + kk);
        const float4 bv1 = *(const float4*)(ab + 128 + kk + 4);
        short8 af, hf;
        af[0] = (short)f2bf(fmaf(av0.x, bf2f((unsigned short)ar[0]), deg * bv0.x));
        af[1] = (short)f2bf(fmaf(av0.y, bf2f((unsigned short)ar[1]), deg * bv0.y));
        af[2] = (short)f2bf(fmaf(av0.z, bf2f((unsigned short)ar[2]), deg * bv0.z));
        af[3] = (short)f2bf(fmaf(av0.w, bf2f((unsigned short)ar[3]), deg * bv0.w));
        af[4] = (short)f2bf(fmaf(av1.x, bf2f((unsigned short)ar[4]), deg * bv1.x));
        af[5] = (short)f2bf(fmaf(av1.y, bf2f((unsigned short)ar[5]), deg * bv1.y));
        af[6] = (short)f2bf(fmaf(av1.z, bf2f((unsigned short)ar[6]), deg * bv1.z));
        af[7] = (short)f2bf(fmaf(av1.w, bf2f((unsigned short)ar[7]), deg * bv1.w));
        hf[0] = (short)f2bf(fmaf(av0.x, bf2f((unsigned short)hr[0]), bv0.x));
        hf[1] = (short)f2bf(fmaf(av0.y, bf2f((unsigned short)hr[1]), bv0.y));
        hf[2] = (short)f2bf(fmaf(av0.z, bf2f((unsigned short)hr[2]), bv0.z));
        hf[3] = (short)f2bf(fmaf(av0.w, bf2f((unsigned short)hr[3]), bv0.w));
        hf[4] = (short)f2bf(fmaf(av1.x, bf2f((unsigned short)hr[4]), bv1.x));
        hf[5] = (short)f2bf(fmaf(av1.y, bf2f((unsigned short)hr[5]), bv1.y));
        hf[6] = (short)f2bf(fmaf(av1.z, bf2f((unsigned short)hr[6]), bv1.z));
        hf[7] = (short)f2bf(fmaf(av1.w, bf2f((unsigned short)hr[7]), bv1.w));
        #pragma unroll
        for (int t = 0; t < 8; ++t) {
            const short8 bgf = *(const short8*)&sB[cur][(t * 64 + lane) * 8];
            const short8 brf = *(const short8*)&sB[cur][4096 + (t * 64 + lane) * 8];
            accg[t] = __builtin_amdgcn_mfma_f32_16x16x32_bf16(af, bgf, accg[t], 0, 0, 0);
            accr[t] = __builtin_amdgcn_mfma_f32_16x16x32_bf16(hf, brf, accr[t], 0, 0, 0);
        }
        __syncthreads();   // next buf staged + everyone done reading cur
        cur ^= 1;
    }

    // epilogue: bias + relu + add, store bf16 h2, fused fp32 BN partial sums
    #pragma unroll
    for (int t = 0; t < 8; ++t) {
        const int c = t * 16 + ln15;
        const float bgc = bg[c];
        const float brc = br[c];
        float sv = 0.f, qv = 0.f;
        #pragma unroll
        for (int r = 0; r < 4; ++r) {
            const int row = r0 + q * 4 + r;
            const float v = fmaxf(accg[t][r] + bgc, 0.f) + fmaxf(accr[t][r] + brc, 0.f);
            h2b[(size_t)row * DD + c] = f2bf(v);
            sv += v; qv += v * v;
        }
        sv += __shfl_xor(sv, 16, 64); sv += __shfl_xor(sv, 32, 64);
        qv += __shfl_xor(qv, 16, 64); qv += __shfl_xor(qv, 32, 64);
        if (q == 0) {
            atomicAdd(&sSum[c], sv);
            atomicAdd(&sSum[128 + c], qv);
        }
    }
    __syncthreads();
    atomicAdd(&sumrep[(blockIdx.x & (NREP - 1)) * 256 + tid], sSum[tid]);
}

// ---------------- BatchNorm normalize (final layer): pure affine, bf16 in fp32 out --
__global__ __launch_bounds__(256) void k_bn(const unsigned short* __restrict__ h2b,
                                            const float* __restrict__ ab,
                                            float* __restrict__ out) {
    const int t = blockIdx.x * 256 + threadIdx.x;  // NN*32 threads
    const size_t base = (size_t)t * 4;
    const int c = (int)(base & 127);
    const ushort4 v = *(const ushort4*)(h2b + base);
    const float4 a = *(const float4*)(ab + c);
    const float4 b = *(const float4*)(ab + 128 + c);
    float4 o;
    o.x = fmaf(a.x, bf2f(v.x), b.x);
    o.y = fmaf(a.y, bf2f(v.y), b.y);
    o.z = fmaf(a.z, bf2f(v.z), b.z);
    o.w = fmaf(a.w, bf2f(v.w), b.w);
    *(float4*)(out + base) = o;
}

extern "C" void kernel_launch(void* const* d_in, const int* in_sizes, int n_in,
                              void* d_out, int out_size, void* d_ws, size_t ws_size,
                              hipStream_t stream) {
    const float* X     = (const float*)d_in[0];
    const int*   src   = (const int*)d_in[1];
    const int*   dst   = (const int*)d_in[2];
    const float* Wi    = (const float*)d_in[3];
    const float* Wg    = (const float*)d_in[4];
    const float* bg    = (const float*)d_in[5];
    const float* Wr    = (const float*)d_in[6];
    const float* br    = (const float*)d_in[7];
    const float* gamma = (const float*)d_in[8];
    const float* beta  = (const float*)d_in[9];
    float* out = (float*)d_out;

    unsigned short* hA   = (unsigned short*)d_ws;         // [NN*DD] bf16
    unsigned short* hB   = hA + (size_t)NN * DD;          // [NN*DD] bf16
    unsigned short* aggb = hB + (size_t)NN * DD;          // [NN*DD] bf16
    float* sumrep = (float*)(aggb + (size_t)NN * DD);     // [NL*NREP*256]
    int* cnt      = (int*)(sumrep + NL * NREP * 256);     // [NN] (adjacent: one zero blk)
    int* offs     = cnt + NN;                             // [NN]
    float* abv    = (float*)(offs + NN);                  // [(NL+1)*2*DD] a/b per stage
    unsigned short* wfrag = (unsigned short*)(abv + (NL + 1) * 2 * DD);  // Wg/Wr frags
    unsigned short* wifrag = wfrag + NL * 2 * 16384;      // [12288] Wi frag (K=96)
    int* rowptr = (int*)(wifrag + 12288);                 // [NN+1]
    int* col    = rowptr + NN + 1;                        // [NE]
    int* bsum   = col + NE;                               // [NB]

    // k_pre: Wi frag prepack + zero sumrep/cnt (replaces memset)
    k_pre<<<NB_PRE, 256, 0, stream>>>(Wi, wifrag, (int*)sumrep);
    k_setup<<<NB_SETUP, 256, 0, stream>>>(X, wifrag, hA, Wg, Wr, wfrag, dst, cnt, abv);
    k_scan1<<<NB, 256, 0, stream>>>(cnt, bsum);
    k_scan3<<<NB, 256, 0, stream>>>(cnt, bsum, rowptr, offs);
    k_fill<<<NE / 256, 256, 0, stream>>>(src, dst, offs, col);

    // bf16 activation ping-pong: hA -> hB -> hA -> hB; k_bn reads final hB
    const unsigned short* hcur = hA;
    unsigned short* h2bufs[NL] = { hB, hA, hB };
    for (int l = 0; l < NL; ++l) {
        unsigned short* h2 = h2bufs[l];
        // gather(l): raw sums; for l>0 one extra block computes abv(l) from sumrep(l-1)
        const int gblocks = NGB + (l > 0 ? 1 : 0);
        k_gather<<<gblocks, 256, 0, stream>>>(hcur, rowptr, col, aggb,
                                              sumrep + (size_t)(l > 0 ? l - 1 : 0) * NREP * 256,
                                              gamma + (l > 0 ? l - 1 : 0) * DD,
                                              beta + (l > 0 ? l - 1 : 0) * DD,
                                              abv + l * 2 * DD);
        k_layer<<<NT, 256, 0, stream>>>(hcur, aggb, rowptr,
                                        wfrag + l * 2 * 16384,
                                        bg + l * DD, br + l * DD,
                                        abv + l * 2 * DD, h2,
                                        sumrep + (size_t)l * NREP * 256);
        hcur = h2;
    }
    // final stats (for k_bn) + normalize
    k_stats<<<1, 128, 0, stream>>>(sumrep + (size_t)(NL - 1) * NREP * 256,
                                   gamma + (NL - 1) * DD, beta + (NL - 1) * DD,
                                   abv + NL * 2 * DD);
    k_bn<<<(NN * 32) / 256, 256, 0, stream>>>(h2bufs[NL - 1], abv + NL * 2 * DD, out);
}

// Round 16
// 246.918 us; speedup vs baseline: 1.0186x; 1.0186x over previous
//
#include <hip/hip_runtime.h>

#define NN 74240      // nodes
#define NE 593920     // edges
#define DIN 75
#define DD 128
#define NL 3
#define EPS 1e-5f
#define NB 290        // scan blocks: 290*256 == NN
#define NT (NN / 64)  // 1160 row-tiles for k_layer
#define NGB (NN / 4)  // 18560 gather blocks
#define NREP 64       // replicated BN-sum buffers
#define SROWX 104     // LDS X row stride (shorts): 208B -> 2-way bank alias (free)

// k_pre block-range dispatch: Wi frag prepack (48) + zero sumrep/cnt (121)
#define NB_WIFRAG 48                       // 12288 shorts / 256
#define NZ4 ((NL * NREP * 256 + NN) / 4)   // 30848 int4-words to zero
#define NB_ZERO  ((NZ4 + 255) / 256)       // 121
#define NB_PRE   (NB_WIFRAG + NB_ZERO)     // 169

// k_setup block-range dispatch
#define NB_INIT  (NN / 64)                // 1160
#define SB_WPREP NB_INIT                  // 1160
#define NB_WPREP ((NL * 2 * 16384) / 256) // 384
#define SB_HIST  (SB_WPREP + NB_WPREP)    // 1544
#define NB_HIST  (NE / 256)               // 2320
#define SB_PREP  (SB_HIST + NB_HIST)      // 3864
#define NB_SETUP (SB_PREP + 1)            // 3865

typedef __attribute__((ext_vector_type(8))) short short8;   // 8 bf16 = 4 VGPRs (MFMA A/B frag)
typedef __attribute__((ext_vector_type(4))) float f32x4;    // MFMA C/D frag

// fp32 -> bf16 with round-to-nearest-even
static __device__ __forceinline__ unsigned short f2bf(float f) {
    union { float f; unsigned u; } v; v.f = f;
    unsigned u = v.u;
    unsigned r = (u + 0x7fffu + ((u >> 16) & 1u)) >> 16;
    return (unsigned short)r;
}

// bf16 -> fp32 (exact)
static __device__ __forceinline__ float bf2f(unsigned short s) {
    union { unsigned u; float f; } v; v.u = ((unsigned)s) << 16; return v.f;
}

// ---------------- pre: Wi frag-prepack (bf16, K padded 75->96) | zero scratch ------
__global__ __launch_bounds__(256) void k_pre(const float* __restrict__ Wi,
                                             unsigned short* __restrict__ wifrag,
                                             int* __restrict__ zbase) {
    const int tid = threadIdx.x;
    const int b = blockIdx.x;
    if (b < NB_WIFRAG) {
        // frag flat idx e = ((s*8+t)*64 + lane)*8 + j ; k=s*32+(lane>>4)*8+j,
        // n=t*16+(lane&15). k>=75 -> 0.
        const int e = b * 256 + tid;
        const int j = e & 7;
        const int lane = (e >> 3) & 63;
        const int st = e >> 9;
        const int s = st >> 3, t = st & 7;
        const int k = s * 32 + (lane >> 4) * 8 + j;
        const int n = t * 16 + (lane & 15);
        wifrag[e] = (k < DIN) ? f2bf(Wi[k * DD + n]) : (unsigned short)0;
    } else {
        const int zi = (b - NB_WIFRAG) * 256 + tid;   // int4 index
        if (zi < NZ4) {
            ((int4*)zbase)[zi] = (int4){0, 0, 0, 0};
        }
    }
}

// ---------------- fused setup: init GEMM (MFMA, frag-fed) | wprep | hist | ab0 -----
__global__ __launch_bounds__(256) void k_setup(const float* __restrict__ X,
                                               const unsigned short* __restrict__ wifrag,
                                               unsigned short* __restrict__ hb,
                                               const float* __restrict__ Wg,
                                               const float* __restrict__ Wr,
                                               unsigned short* __restrict__ wf,
                                               const int* __restrict__ dst,
                                               int* __restrict__ cnt,
                                               float* __restrict__ ab0) {
    __shared__ unsigned short sXb[64 * SROWX];    // 13312 B (init branch only)
    const int tid = threadIdx.x;
    const int b = blockIdx.x;
    if (b < NB_INIT) {
        // ---- init GEMM via MFMA: h_bf16 = bf16(X @ W_init), K padded 75->96 ----
        const int r0 = b * 64;
        {   // stage 64x75 X: coalesced float4 (1200 vecs) + computed row/col
            const float4* Xv = (const float4*)(X + (size_t)r0 * DIN);  // 16B-aligned
            #pragma unroll
            for (int i = 0; i < 5; ++i) {
                const int vi = tid + i * 256;
                if (vi < 1200) {
                    const float4 v = Xv[vi];
                    const int f0 = vi * 4;
                    int r = f0 / 75;
                    int c = f0 - r * 75;
                    sXb[r * SROWX + c] = f2bf(v.x);
                    ++c; if (c == DIN) { c = 0; ++r; } sXb[r * SROWX + c] = f2bf(v.y);
                    ++c; if (c == DIN) { c = 0; ++r; } sXb[r * SROWX + c] = f2bf(v.z);
                    ++c; if (c == DIN) { c = 0; ++r; } sXb[r * SROWX + c] = f2bf(v.w);
                }
            }
            // zero pad cols 75..103 (29 per row)
            for (int p = tid; p < 64 * (SROWX - DIN); p += 256) {
                const int r = p / (SROWX - DIN);
                const int c = DIN + (p - r * (SROWX - DIN));
                sXb[r * SROWX + c] = 0;
            }
        }
        __syncthreads();
        const int w = tid >> 6;
        const int lane = tid & 63;
        const int ln15 = lane & 15;
        const int q = lane >> 4;
        const short8* __restrict__ wif = (const short8*)wifrag;   // 1536 short8
        f32x4 acc[8];
        #pragma unroll
        for (int t = 0; t < 8; ++t) acc[t] = (f32x4){0.f, 0.f, 0.f, 0.f};
        #pragma unroll
        for (int s = 0; s < 3; ++s) {
            const int ks = s * 32 + q * 8;
            const short8 af = *(const short8*)&sXb[(w * 16 + ln15) * SROWX + ks];
            #pragma unroll
            for (int t = 0; t < 8; ++t) {
                const short8 bfr = wif[(s * 8 + t) * 64 + lane];
                acc[t] = __builtin_amdgcn_mfma_f32_16x16x32_bf16(af, bfr, acc[t], 0, 0, 0);
            }
        }
        // C/D: col = t*16+ln15, row = r0 + w*16 + q*4 + r
        #pragma unroll
        for (int t = 0; t < 8; ++t) {
            #pragma unroll
            for (int r = 0; r < 4; ++r) {
                hb[(size_t)(r0 + w * 16 + q * 4 + r) * DD + t * 16 + ln15] = f2bf(acc[t][r]);
            }
        }
    } else if (b < SB_HIST) {
        // ---- weight prepack: fp32 [k][n] -> frag-ordered bf16 (consumed by k_layer) --
        const int gt = (b - SB_WPREP) * 256 + tid;
        const int l = gt >> 15;
        const int m = (gt >> 14) & 1;
        const int e = gt & 16383;
        const int k = e >> 7, n = e & 127;
        const float* W = (m == 0 ? Wg : Wr) + l * 16384;
        const float v = W[e];
        const int s = k >> 5, q = (k >> 3) & 3, j = k & 7, t = n >> 4;
        const int ln = (q << 4) | (n & 15);
        const int idx = ((s * 8 + t) * 64 + ln) * 8 + j;
        wf[(l * 2 + m) * 16384 + idx] = f2bf(v);
    } else if (b < SB_PREP) {
        // ---- degree histogram ----
        const int e = (b - SB_HIST) * 256 + tid;
        atomicAdd(&cnt[dst[e]], 1);
    } else {
        // ---- identity affine for layer-0 input ----
        ab0[tid] = (tid < 128) ? 1.0f : 0.0f;
    }
}

// ---------------- CSR build: scan1 -> scan3 (bsum-based parallel prefix) -> fill ----
// (round-10 lesson: merging these turns the bsum prefix into a 289-iter serial chain)
__global__ __launch_bounds__(256) void k_scan1(const int* __restrict__ cnt,
                                               int* __restrict__ bsum) {
    const int tid = threadIdx.x;
    int v = cnt[blockIdx.x * 256 + tid];
    #pragma unroll
    for (int off = 1; off < 64; off <<= 1) v += __shfl_xor(v, off, 64);
    __shared__ int ws[4];
    if ((tid & 63) == 0) ws[tid >> 6] = v;
    __syncthreads();
    if (tid == 0) bsum[blockIdx.x] = ws[0] + ws[1] + ws[2] + ws[3];
}

__global__ __launch_bounds__(256) void k_scan3(const int* __restrict__ cnt,
                                               const int* __restrict__ bsum,
                                               int* __restrict__ rowptr,
                                               int* __restrict__ offs) {
    const int tid = threadIdx.x;
    const int b = blockIdx.x;
    const int t = b * 256 + tid;
    const int lane = tid & 63;
    __shared__ int ws[4];
    __shared__ int ws2[4];
    __shared__ int sBoff;
    // exclusive block base (parallel over threads: <=2 elements each)
    int part = 0;
    for (int i = tid; i < b; i += 256) part += bsum[i];
    #pragma unroll
    for (int off = 1; off < 64; off <<= 1) part += __shfl_xor(part, off, 64);
    if (lane == 0) ws2[tid >> 6] = part;
    __syncthreads();
    if (tid == 0) sBoff = ws2[0] + ws2[1] + ws2[2] + ws2[3];
    // in-block inclusive scan of cnt
    const int v = cnt[t];
    int inc = v;
    #pragma unroll
    for (int off = 1; off < 64; off <<= 1) {
        const int u = __shfl_up(inc, off, 64);
        if (lane >= off) inc += u;
    }
    if (lane == 63) ws[tid >> 6] = inc;
    __syncthreads();
    const int w = tid >> 6;
    int waveoff = 0;
    for (int i = 0; i < 4; ++i) waveoff += (i < w) ? ws[i] : 0;
    const int excl = sBoff + waveoff + inc - v;
    rowptr[t] = excl;
    offs[t] = excl;
    if (b == NB - 1 && tid == 255) rowptr[NN] = NE;
}

__global__ __launch_bounds__(256) void k_fill(const int* __restrict__ src,
                                              const int* __restrict__ dst,
                                              int* offs, int* __restrict__ col) {
    const int e = blockIdx.x * 256 + threadIdx.x;   // grid == NE
    const int pos = atomicAdd(&offs[dst[e]], 1);
    col[pos] = src[e];
}

// reduce NREP replicated partial-sum buffers -> affine (a,b); standalone copy used
// only for the FINAL stage (k_bn input). Per-layer stats ride inside k_gather.
__global__ __launch_bounds__(128) void k_stats(const float* __restrict__ srep,
                                               const float* __restrict__ gamma,
                                               const float* __restrict__ beta,
                                               float* __restrict__ ab) {
    const int c = threadIdx.x;
    float s = 0.f, q = 0.f;
    for (int r = 0; r < NREP; ++r) {
        s += srep[r * 256 + c];
        q += srep[r * 256 + 128 + c];
    }
    const float invN = 1.0f / (float)NN;
    const float mu = s * invN;
    const float var = q * invN - mu * mu;
    const float a = gamma[c] * rsqrtf(var + EPS);
    ab[c] = a;
    ab[128 + c] = beta[c] - a * mu;
}

// ---------------- gather (RAW sums): aggb[row] = bf16(sum_e hb[col[e]]) -------------
// Predicated 4-wide loop (round-14 best). Round-15 A/B: 8-wide was null-to-worse
// (L3-random-issue-bound; extra clamped loads + VGPRs cost what they saved) -- keep
// 4-wide. Masked fmaf accumulate = bit-identical math.
__global__ __launch_bounds__(256) void k_gather(const unsigned short* __restrict__ hb,
                                                const int* __restrict__ rowptr,
                                                const int* __restrict__ col,
                                                unsigned short* __restrict__ aggb,
                                                const float* __restrict__ srep,
                                                const float* __restrict__ gamma,
                                                const float* __restrict__ beta,
                                                float* __restrict__ abn) {
    if (blockIdx.x >= NGB) {
        // ---- fused BN-stats for the upcoming layer (1 block, 128 lanes) ----
        const int c = threadIdx.x;
        if (c < 128) {
            float s = 0.f, q = 0.f;
            for (int r = 0; r < NREP; ++r) {
                s += srep[r * 256 + c];
                q += srep[r * 256 + 128 + c];
            }
            const float invN = 1.0f / (float)NN;
            const float mu = s * invN;
            const float var = q * invN - mu * mu;
            const float a = gamma[c] * rsqrtf(var + EPS);
            abn[c] = a;
            abn[128 + c] = beta[c] - a * mu;
        }
        return;
    }
    const int wave = threadIdx.x >> 6;
    const int lane = threadIdx.x & 63;
    const int row = blockIdx.x * 4 + wave;   // one row per wave (round-5 lesson)
    const int eb = rowptr[row];
    const int ee = rowptr[row + 1];
    const int half = lane >> 5;
    const int f = (lane & 31) * 4;           // 4 channels per lane
    float4 a0 = {0.f,0.f,0.f,0.f}, a1 = {0.f,0.f,0.f,0.f};
    float4 a2 = {0.f,0.f,0.f,0.f}, a3 = {0.f,0.f,0.f,0.f};
    for (int e = eb + half; e < ee; e += 8) {
        const int e1 = e + 2, e2 = e + 4, e3 = e + 6;
        const int c0 = col[e];
        const int c1 = col[e1 < ee ? e1 : e];     // clamp to a valid edge
        const int c2 = col[e2 < ee ? e2 : e];
        const int c3 = col[e3 < ee ? e3 : e];
        const float m1 = (e1 < ee) ? 1.0f : 0.0f; // mask the accumulate
        const float m2 = (e2 < ee) ? 1.0f : 0.0f;
        const float m3 = (e3 < ee) ? 1.0f : 0.0f;
        const ushort4 v0 = *(const ushort4*)(hb + (size_t)c0 * DD + f);
        const ushort4 v1 = *(const ushort4*)(hb + (size_t)c1 * DD + f);
        const ushort4 v2 = *(const ushort4*)(hb + (size_t)c2 * DD + f);
        const ushort4 v3 = *(const ushort4*)(hb + (size_t)c3 * DD + f);
        a0.x += bf2f(v0.x); a0.y += bf2f(v0.y); a0.z += bf2f(v0.z); a0.w += bf2f(v0.w);
        a1.x = fmaf(m1, bf2f(v1.x), a1.x); a1.y = fmaf(m1, bf2f(v1.y), a1.y);
        a1.z = fmaf(m1, bf2f(v1.z), a1.z); a1.w = fmaf(m1, bf2f(v1.w), a1.w);
        a2.x = fmaf(m2, bf2f(v2.x), a2.x); a2.y = fmaf(m2, bf2f(v2.y), a2.y);
        a2.z = fmaf(m2, bf2f(v2.z), a2.z); a2.w = fmaf(m2, bf2f(v2.w), a2.w);
        a3.x = fmaf(m3, bf2f(v3.x), a3.x); a3.y = fmaf(m3, bf2f(v3.y), a3.y);
        a3.z = fmaf(m3, bf2f(v3.z), a3.z); a3.w = fmaf(m3, bf2f(v3.w), a3.w);
    }
    float4 s;
    s.x = (a0.x + a1.x) + (a2.x + a3.x);
    s.y = (a0.y + a1.y) + (a2.y + a3.y);
    s.z = (a0.z + a1.z) + (a2.z + a3.z);
    s.w = (a0.w + a1.w) + (a2.w + a3.w);
    s.x += __shfl_xor(s.x, 32, 64);
    s.y += __shfl_xor(s.y, 32, 64);
    s.z += __shfl_xor(s.z, 32, 64);
    s.w += __shfl_xor(s.w, 32, 64);
    if (half == 0) {
        ushort4 o;
        o.x = f2bf(s.x);
        o.y = f2bf(s.y);
        o.z = f2bf(s.z);
        o.w = f2bf(s.w);
        *(ushort4*)(aggb + (size_t)row * DD + f) = o;
    }
}

// ---------------- fused layer GEMMs via bf16 MFMA (LDS-staged B, double-buffered) ---
// One 64-row tile per block; per-s-step cooperative B staging (round-12 win).
// Affine applied HERE to both operands: agg (raw sums, needs deg*b) and hin.
#define STAGE(bf, ss) do {                                              \
    _Pragma("unroll")                                                   \
    for (int i_ = 0; i_ < 4; ++i_) {                                    \
        const int idx_ = tid + i_ * 256;                                \
        const uint4 v_ = (idx_ < 512) ? wg_u4[(ss) * 512 + idx_]        \
                                      : wr_u4[(ss) * 512 + idx_ - 512]; \
        ((uint4*)sB[bf])[idx_] = v_;                                    \
    }                                                                   \
} while (0)

__global__ __launch_bounds__(256, 4) void k_layer(const unsigned short* __restrict__ hin,
                                                  const unsigned short* __restrict__ aggb,
                                                  const int* __restrict__ rowptr,
                                                  const unsigned short* __restrict__ wfrag,
                                                  const float* __restrict__ bg,
                                                  const float* __restrict__ br,
                                                  const float* __restrict__ ab,
                                                  unsigned short* __restrict__ h2b,
                                                  float* __restrict__ sumrep) {
    __shared__ unsigned short sB[2][8192];   // [buf][bg(4096) | br(4096)] = 16KB/buf
    __shared__ float sSum[256];
    const int tid = threadIdx.x;
    sSum[tid] = 0.0f;

    const int w = tid >> 6;          // wave 0..3
    const int lane = tid & 63;
    const int ln15 = lane & 15;
    const int q = lane >> 4;
    const int r0 = blockIdx.x * 64 + w * 16;   // wave's 16-row M-tile base
    const int arow = r0 + ln15;                // row this lane's A/H frag holds
    const float deg = (float)(rowptr[arow + 1] - rowptr[arow]);   // L2-hot

    const uint4* __restrict__ wg_u4 = (const uint4*)wfrag;   // 2048 uint4 (Wg frags)
    const uint4* __restrict__ wr_u4 = wg_u4 + 2048;          // Wr frags

    f32x4 accg[8], accr[8];
    #pragma unroll
    for (int t = 0; t < 8; ++t) {
        accg[t] = (f32x4){0.f, 0.f, 0.f, 0.f};
        accr[t] = (f32x4){0.f, 0.f, 0.f, 0.f};
    }

    STAGE(0, 0);
    __syncthreads();
    int cur = 0;

    #pragma unroll
    for (int s = 0; s < 4; ++s) {
        if (s < 3) STAGE(cur ^ 1, s + 1);   // async-issue next step's frags
        const int kk = s * 32 + q * 8;
        const short8 ar = *(const short8*)(aggb + (size_t)arow * DD + kk);  // raw sums
        const short8 hr = *(const short8*)(hin + (size_t)arow * DD + kk);
        const float4 av0 = *(const float4*)(ab + kk);
        const float4 av1 = *(const float4*)(ab + kk + 4);
        const float4 bv0 = *(const float4*)(ab + 128 + kk);
        const float4 bv1 = *(const float4*)(ab + 128 + kk + 4);
        short8 af, hf;
        af[0] = (short)f2bf(fmaf(av0.x, bf2f((unsigned short)ar[0]), deg * bv0.x));
        af[1] = (short)f2bf(fmaf(av0.y, bf2f((unsigned short)ar[1]), deg * bv0.y));
        af[2] = (short)f2bf(fmaf(av0.z, bf2f((unsigned short)ar[2]), deg * bv0.z));
        af[3] = (short)f2bf(fmaf(av0.w, bf2f((unsigned short)ar[3]), deg * bv0.w));
        af[4] = (short)f2bf(fmaf(av1.x, bf2f((unsigned short)ar[4]), deg * bv1.x));
        af[5] = (short)f2bf(fmaf(av1.y, bf2f((unsigned short)ar[5]), deg * bv1.y));
        af[6] = (short)f2bf(fmaf(av1.z, bf2f((unsigned short)ar[6]), deg * bv1.z));
        af[7] = (short)f2bf(fmaf(av1.w, bf2f((unsigned short)ar[7]), deg * bv1.w));
        hf[0] = (short)f2bf(fmaf(av0.x, bf2f((unsigned short)hr[0]), bv0.x));
        hf[1] = (short)f2bf(fmaf(av0.y, bf2f((unsigned short)hr[1]), bv0.y));
        hf[2] = (short)f2bf(fmaf(av0.z, bf2f((unsigned short)hr[2]), bv0.z));
        hf[3] = (short)f2bf(fmaf(av0.w, bf2f((unsigned short)hr[3]), bv0.w));
        hf[4] = (short)f2bf(fmaf(av1.x, bf2f((unsigned short)hr[4]), bv1.x));
        hf[5] = (short)f2bf(fmaf(av1.y, bf2f((unsigned short)hr[5]), bv1.y));
        hf[6] = (short)f2bf(fmaf(av1.z, bf2f((unsigned short)hr[6]), bv1.z));
        hf[7] = (short)f2bf(fmaf(av1.w, bf2f((unsigned short)hr[7]), bv1.w));
        #pragma unroll
        for (int t = 0; t < 8; ++t) {
            const short8 bgf = *(const short8*)&sB[cur][(t * 64 + lane) * 8];
            const short8 brf = *(const short8*)&sB[cur][4096 + (t * 64 + lane) * 8];
            accg[t] = __builtin_amdgcn_mfma_f32_16x16x32_bf16(af, bgf, accg[t], 0, 0, 0);
            accr[t] = __builtin_amdgcn_mfma_f32_16x16x32_bf16(hf, brf, accr[t], 0, 0, 0);
        }
        __syncthreads();   // next buf staged + everyone done reading cur
        cur ^= 1;
    }

    // epilogue: bias + relu + add, store bf16 h2, fused fp32 BN partial sums
    #pragma unroll
    for (int t = 0; t < 8; ++t) {
        const int c = t * 16 + ln15;
        const float bgc = bg[c];
        const float brc = br[c];
        float sv = 0.f, qv = 0.f;
        #pragma unroll
        for (int r = 0; r < 4; ++r) {
            const int row = r0 + q * 4 + r;
            const float v = fmaxf(accg[t][r] + bgc, 0.f) + fmaxf(accr[t][r] + brc, 0.f);
            h2b[(size_t)row * DD + c] = f2bf(v);
            sv += v; qv += v * v;
        }
        sv += __shfl_xor(sv, 16, 64); sv += __shfl_xor(sv, 32, 64);
        qv += __shfl_xor(qv, 16, 64); qv += __shfl_xor(qv, 32, 64);
        if (q == 0) {
            atomicAdd(&sSum[c], sv);
            atomicAdd(&sSum[128 + c], qv);
        }
    }
    __syncthreads();
    atomicAdd(&sumrep[(blockIdx.x & (NREP - 1)) * 256 + tid], sSum[tid]);
}

// ---------------- BatchNorm normalize (final layer): pure affine, bf16 in fp32 out --
__global__ __launch_bounds__(256) void k_bn(const unsigned short* __restrict__ h2b,
                                            const float* __restrict__ ab,
                                            float* __restrict__ out) {
    const int t = blockIdx.x * 256 + threadIdx.x;  // NN*32 threads
    const size_t base = (size_t)t * 4;
    const int c = (int)(base & 127);
    const ushort4 v = *(const ushort4*)(h2b + base);
    const float4 a = *(const float4*)(ab + c);
    const float4 b = *(const float4*)(ab + 128 + c);
    float4 o;
    o.x = fmaf(a.x, bf2f(v.x), b.x);
    o.y = fmaf(a.y, bf2f(v.y), b.y);
    o.z = fmaf(a.z, bf2f(v.z), b.z);
    o.w = fmaf(a.w, bf2f(v.w), b.w);
    *(float4*)(out + base) = o;
}

extern "C" void kernel_launch(void* const* d_in, const int* in_sizes, int n_in,
                              void* d_out, int out_size, void* d_ws, size_t ws_size,
                              hipStream_t stream) {
    const float* X     = (const float*)d_in[0];
    const int*   src   = (const int*)d_in[1];
    const int*   dst   = (const int*)d_in[2];
    const float* Wi    = (const float*)d_in[3];
    const float* Wg    = (const float*)d_in[4];
    const float* bg    = (const float*)d_in[5];
    const float* Wr    = (const float*)d_in[6];
    const float* br    = (const float*)d_in[7];
    const float* gamma = (const float*)d_in[8];
    const float* beta  = (const float*)d_in[9];
    float* out = (float*)d_out;

    unsigned short* hA   = (unsigned short*)d_ws;         // [NN*DD] bf16
    unsigned short* hB   = hA + (size_t)NN * DD;          // [NN*DD] bf16
    unsigned short* aggb = hB + (size_t)NN * DD;          // [NN*DD] bf16
    float* sumrep = (float*)(aggb + (size_t)NN * DD);     // [NL*NREP*256]
    int* cnt      = (int*)(sumrep + NL * NREP * 256);     // [NN] (adjacent: one zero blk)
    int* offs     = cnt + NN;                             // [NN]
    float* abv    = (float*)(offs + NN);                  // [(NL+1)*2*DD] a/b per stage
    unsigned short* wfrag = (unsigned short*)(abv + (NL + 1) * 2 * DD);  // Wg/Wr frags
    unsigned short* wifrag = wfrag + NL * 2 * 16384;      // [12288] Wi frag (K=96)
    int* rowptr = (int*)(wifrag + 12288);                 // [NN+1]
    int* col    = rowptr + NN + 1;                        // [NE]
    int* bsum   = col + NE;                               // [NB]

    // k_pre: Wi frag prepack + zero sumrep/cnt (replaces memset)
    k_pre<<<NB_PRE, 256, 0, stream>>>(Wi, wifrag, (int*)sumrep);
    k_setup<<<NB_SETUP, 256, 0, stream>>>(X, wifrag, hA, Wg, Wr, wfrag, dst, cnt, abv);
    k_scan1<<<NB, 256, 0, stream>>>(cnt, bsum);
    k_scan3<<<NB, 256, 0, stream>>>(cnt, bsum, rowptr, offs);
    k_fill<<<NE / 256, 256, 0, stream>>>(src, dst, offs, col);

    // bf16 activation ping-pong: hA -> hB -> hA -> hB; k_bn reads final hB
    const unsigned short* hcur = hA;
    unsigned short* h2bufs[NL] = { hB, hA, hB };
    for (int l = 0; l < NL; ++l) {
        unsigned short* h2 = h2bufs[l];
        // gather(l): raw sums; for l>0 one extra block computes abv(l) from sumrep(l-1)
        const int gblocks = NGB + (l > 0 ? 1 : 0);
        k_gather<<<gblocks, 256, 0, stream>>>(hcur, rowptr, col, aggb,
                                              sumrep + (size_t)(l > 0 ? l - 1 : 0) * NREP * 256,
                                              gamma + (l > 0 ? l - 1 : 0) * DD,
                                              beta + (l > 0 ? l - 1 : 0) * DD,
                                              abv + l * 2 * DD);
        k_layer<<<NT, 256, 0, stream>>>(hcur, aggb, rowptr,
                                        wfrag + l * 2 * 16384,
                                        bg + l * DD, br + l * DD,
                                        abv + l * 2 * DD, h2,
                                        sumrep + (size_t)l * NREP * 256);
        hcur = h2;
    }
    // final stats (for k_bn) + normalize
    k_stats<<<1, 128, 0, stream>>>(sumrep + (size_t)(NL - 1) * NREP * 256,
                                   gamma + (NL - 1) * DD, beta + (NL - 1) * DD,
                                   abv + NL * 2 * DD);
    k_bn<<<(NN * 32) / 256, 256, 0, stream>>>(h2bufs[NL - 1], abv + NL * 2 * DD, out);
}